// Round 14
// baseline (161.188 us; speedup 1.0000x reference)
//
#include <hip/hip_runtime.h>
#include <stdint.h>

// Fused attention head: out = softmax(mask((Tgt@Wq)(Src@Wk)^T * H^-0.5)) @ (Src@Wv)
// B=4096, T=128, C=128, H=64. One block/batch, 512 threads (8 waves).
// R14 = R13 (champion, 140.9us) with double-buffered staging: ping-pong X0/X1
// + two pf register sets -> 5 barriers instead of 8, 8 outstanding staging
// loads at head (2x MLP). LDS = X0,X1,Kb,Vb,Qb = 80KB exactly (2 blocks/CU);
// BIAS moved out of LDS -> computed in tail from L2-resident mask loads that
// hide under QK MFMAs. P-bounce slices in dead X0∪X1 (same formulas).

typedef uint32_t u32x2 __attribute__((ext_vector_type(2)));
typedef uint32_t u32x4 __attribute__((ext_vector_type(4)));
typedef float    f32x4 __attribute__((ext_vector_type(4)));
typedef __bf16   bf16x8 __attribute__((ext_vector_type(8)));

static __device__ __forceinline__ uint32_t pack2(float a, float b) {  // RNE (prep kernel)
  uint32_t ua = __builtin_bit_cast(uint32_t, a);
  uint32_t ub = __builtin_bit_cast(uint32_t, b);
  ua += 0x7FFFu + ((ua >> 16) & 1u);
  ub += 0x7FFFu + ((ub >> 16) & 1u);
  return (ua >> 16) | (ub & 0xFFFF0000u);
}
// compiler-generated f32->bf16 RNE pair (HW-proven R9-R13)
static __device__ __forceinline__ uint32_t cvt2(float a, float b) {
  uint16_t lo = __builtin_bit_cast(uint16_t, (__bf16)a);
  uint16_t hi = __builtin_bit_cast(uint16_t, (__bf16)b);
  return (uint32_t)lo | ((uint32_t)hi << 16);
}
static __device__ __forceinline__ f32x4 mfma16(u32x4 a, u32x4 b, f32x4 c) {
  return __builtin_amdgcn_mfma_f32_16x16x32_bf16(
      __builtin_bit_cast(bf16x8, a), __builtin_bit_cast(bf16x8, b), c, 0, 0, 0);
}

// ---- prep: pack Wq/Wk/Wv into MFMA frag layout in ws; detect mask dtype ----
// frag f=(m*4+ct)*4+ks, lane l: 8 bf16 of W[c][h], h=ct*16+(l&15), c=ks*32+(l>>4)*8+0..7.
// Serves BOTH as B-frag of W (V proj) and A-frag of W^T (K/Q proj).
__global__ void prep_w(const float* __restrict__ Wq, const float* __restrict__ Wk,
                       const float* __restrict__ Wv, const void* __restrict__ mask,
                       uint32_t* __restrict__ ws) {
  const int blk = blockIdx.x;
  const int l = threadIdx.x;  // 0..63
  if (blk < 48) {
    const int m  = blk >> 4;
    const int ct = (blk >> 2) & 3;
    const int ks = blk & 3;
    const float* W = (m == 0) ? Wq : ((m == 1) ? Wk : Wv);
    const int h  = ct * 16 + (l & 15);
    const int c0 = ks * 32 + (l >> 4) * 8;
    u32x4 v;
#pragma unroll
    for (int p = 0; p < 4; ++p)
      v[p] = pack2(W[(c0 + 2 * p) * 64 + h], W[(c0 + 2 * p + 1) * 64 + h]);
    ((u32x4*)ws)[blk * 64 + l] = v;
  } else {
    // mask dtype detect: 0=int32(0/1), 1=bytes, 2=float
    const uint32_t* mw = (const uint32_t*)mask;
    int fl = 0;
    for (int i = l * 16; i < l * 16 + 16; ++i) {
      uint32_t x = mw[i];
      if (x == 0x3F800000u) fl = 2;
      else if (x > 1u && fl != 2) fl = 1;
    }
#pragma unroll
    for (int off = 32; off > 0; off >>= 1) {
      int o = __shfl_down(fl, off);
      fl = (o > fl) ? o : fl;
    }
    if (l == 0) ws[12288] = (uint32_t)fl;
  }
}

// LDS (80 KB exactly -> 2 blocks/CU):
//  X0  [64][128] bf16 swz (16K)  ping staging; tail: wave-private P rows tl 0..7
//  X1  [64][128] bf16 swz (16K)  pong staging; tail: wave-private P rows tl 8..15
//  Kb  [128][64] bf16 swz (16K)  K^T
//  Vb  [64][128] bf16 swz (16K)  V^T[h][s]
//  Qb  [128][64] bf16 swz (16K)  Q^T
// Swizzle: 16B chunk c of row r stored at chunk (c ^ (r&7)); P uses (c ^ (t&15)).
__global__ __launch_bounds__(512, 2) void attn_fused(
    const float* __restrict__ src, const float* __restrict__ tgt,
    const void* __restrict__ mask, const uint32_t* __restrict__ ws,
    float* __restrict__ out) {
  __shared__ __align__(16) uint8_t lds[81920];
  uint8_t* const X0 = lds;
  uint8_t* const X1 = lds + 16384;
  uint8_t* const Kb = lds + 32768;
  uint8_t* const Vb = lds + 49152;
  uint8_t* const Qb = lds + 65536;

  const int b   = blockIdx.x;
  const int tid = (int)threadIdx.x;
  const int l   = tid & 63;
  const int w   = tid >> 6;      // wave 0..7
  const int l15 = l & 15;
  const int g4  = l >> 4;        // 0..3
  const int ct  = w & 3;         // this wave's h-tile for projections
  const int sg  = (w >> 2) * 2;  // first local s/t-tile (0 or 2)

  const u32x4* wsv = (const u32x4*)ws;
  const int mflag = (int)ws[12288];
  const float* const srcb = src + (size_t)b * 16384;
  const float* const tgtb = tgt + (size_t)b * 16384;

  u32x4 wk[4], wv[4], wq[4];
#pragma unroll
  for (int ks = 0; ks < 4; ++ks) {
    wk[ks] = wsv[((4 + ct) * 4 + ks) * 64 + l];   // A-frag of Wk^T
    wv[ks] = wsv[((8 + ct) * 4 + ks) * 64 + l];   // B-frag of Wv
  }

  // staging: thread covers 4 fully-coalesced f32x4 chunks (tid + p*512);
  // TWO register sets (pfA/pfB) -> every stage_write's data loaded >=1 phase early
  f32x4 pfA[4], pfB[4];
  auto stage_load = [&](const float* gbase, f32x4* pf) {
#pragma unroll
    for (int p = 0; p < 4; ++p)
      pf[p] = *(const f32x4*)(gbase + tid * 4 + p * 2048);
  };
  auto stage_write = [&](uint8_t* X, const f32x4* pf) {
#pragma unroll
    for (int p = 0; p < 4; ++p) {
      const int c   = tid + p * 512;
      const int row = c >> 5;     // 0..63
      const int cc  = c & 31;     // f32x4 chunk within row
      u32x2 d = { cvt2(pf[p][0], pf[p][1]), cvt2(pf[p][2], pf[p][3]) };
      *(u32x2*)(X + (row << 8) + ((((cc >> 1) ^ (row & 7))) << 4) + ((cc & 1) << 3)) = d;
    }
  };

  // K^T = Wk^T @ Src^T and V = Src @ Wv over one staged 64-row half in E.
  auto projKV = [&](const uint8_t* E, int half) {
#pragma unroll
    for (int i = 0; i < 2; ++i) {
      const int st  = sg + i;            // local 16-row tile 0..3
      const int row = st * 16 + l15;     // E row
      f32x4 cK = {0, 0, 0, 0}, cV = {0, 0, 0, 0};
#pragma unroll
      for (int ks = 0; ks < 4; ++ks) {
        u32x4 e = *(const u32x4*)(E + (row << 8) + ((((ks * 4 + g4) ^ (row & 7))) << 4));
        cK = mfma16(wk[ks], e, cK);   // C[h][s]
        cV = mfma16(e, wv[ks], cV);   // C[s][h]
      }
      const int s  = half * 64 + st * 16 + l15;       // K^T: n=s per-lane col
      const int h0 = ct * 16 + g4 * 4;                //      m=h rows (packed)
      u32x2 dk = { cvt2(cK[0], cK[1]), cvt2(cK[2], cK[3]) };
      *(u32x2*)(Kb + (s << 7) + ((((h0 >> 3) ^ (s & 7))) << 4) + ((h0 & 7) << 1)) = dk;
      const int s0 = half * 64 + st * 16 + g4 * 4;    // V: m=s rows (packed)
      const int h  = ct * 16 + l15;                   //    n=h per-lane col
      u32x2 dv = { cvt2(cV[0], cV[1]), cvt2(cV[2], cV[3]) };
      *(u32x2*)(Vb + (h << 8) + ((((s0 >> 3) ^ (h & 7))) << 4) + ((s0 & 7) << 1)) = dv;
    }
  };
  auto projQ = [&](const uint8_t* E, int half) {
#pragma unroll
    for (int i = 0; i < 2; ++i) {
      const int st  = sg + i;
      const int row = st * 16 + l15;
      f32x4 cQ = {0, 0, 0, 0};
#pragma unroll
      for (int ks = 0; ks < 4; ++ks) {
        u32x4 e = *(const u32x4*)(E + (row << 8) + ((((ks * 4 + g4) ^ (row & 7))) << 4));
        cQ = mfma16(wq[ks], e, cQ);
      }
      const int t  = half * 64 + st * 16 + l15;
      const int h0 = ct * 16 + g4 * 4;
      u32x2 dq = { cvt2(cQ[0], cQ[1]), cvt2(cQ[2], cQ[3]) };
      *(u32x2*)(Qb + (t << 7) + ((((h0 >> 3) ^ (t & 7))) << 4) + ((h0 & 7) << 1)) = dq;
    }
  };

  // ---- 5-barrier ping-pong pipeline ----
  stage_load(srcb, pfA);
  stage_load(srcb + 8192, pfB);    // 8 chunks in flight at head
  stage_write(X0, pfA);
  __syncthreads();                 // B1: X0(srcA) ready
  stage_load(tgtb, pfA);           // tgtA in flight over this phase
  projKV(X0, 0);
  stage_write(X1, pfB);            // srcB (loaded at head)
  __syncthreads();                 // B2: X1 ready; X0 reads done
  stage_load(tgtb + 8192, pfB);    // tgtB in flight
  projKV(X1, 1);
#pragma unroll
  for (int ks = 0; ks < 4; ++ks)
    wq[ks] = wsv[(ct * 4 + ks) * 64 + l];  // A-frag of Wq^T (wk/wv soon dead)
  stage_write(X0, pfA);            // tgtA
  __syncthreads();                 // B3: X0 ready; X1 reads done
  projQ(X0, 0);
  stage_write(X1, pfB);            // tgtB
  __syncthreads();                 // B4: X1 ready; X0 reads done
  projQ(X1, 1);
  __syncthreads();                 // B5: Qb/Kb/Vb complete; X0/X1 dead
  // ---- free-run tail: no more barriers ----

  // pad-mask bias from L2-resident mask (loads issue here, hide under QK)
  f32x4 bias[8];
#pragma unroll
  for (int mt = 0; mt < 8; ++mt) {
    const int s0 = mt * 16 + g4 * 4;
    if (mflag == 0) {
      u32x4 mi = *(const u32x4*)((const int*)mask + (size_t)b * 128 + s0);
#pragma unroll
      for (int r = 0; r < 4; ++r) bias[mt][r] = mi[r] ? 0.0f : -1e30f;
    } else if (mflag == 1) {
      uint32_t mi = *(const uint32_t*)((const uint8_t*)mask + (size_t)b * 128 + s0);
#pragma unroll
      for (int r = 0; r < 4; ++r) bias[mt][r] = ((mi >> (8 * r)) & 0xFFu) ? 0.0f : -1e30f;
    } else {
      f32x4 mv = *(const f32x4*)((const float*)mask + (size_t)b * 128 + s0);
#pragma unroll
      for (int r = 0; r < 4; ++r) bias[mt][r] = (mv[r] != 0.0f) ? 0.0f : -1e30f;
    }
  }

  // S^T = K @ Q^T : wave w owns t-tile w. Per lane: col t = 16w + l15,
  // rows s = mt*16 + g4*4 + r  (C layout: col = lane&15, row = (lane>>4)*4 + reg).
  const int tq = 16 * w + l15;
  u32x4 qf0 = *(const u32x4*)(Qb + (tq << 7) + (((g4 ^ (tq & 7))) << 4));
  u32x4 qf1 = *(const u32x4*)(Qb + (tq << 7) + ((((4 + g4) ^ (tq & 7))) << 4));

  f32x4 sacc[8];
#pragma unroll
  for (int mt = 0; mt < 8; ++mt) sacc[mt] = {0, 0, 0, 0};
  __builtin_amdgcn_s_setprio(1);
#pragma unroll
  for (int mt = 0; mt < 8; ++mt) {
    const int srow = mt * 16 + l15;
    u32x4 k0 = *(const u32x4*)(Kb + (srow << 7) + (((g4 ^ (srow & 7))) << 4));
    u32x4 k1 = *(const u32x4*)(Kb + (srow << 7) + ((((4 + g4) ^ (srow & 7))) << 4));
    sacc[mt] = mfma16(k0, qf0, sacc[mt]);
    sacc[mt] = mfma16(k1, qf1, sacc[mt]);
  }
  __builtin_amdgcn_s_setprio(0);

  // softmax over s (per lane: 32 s-values of row t; reduce across 4-lane group)
  float m = -3.0e38f;
#pragma unroll
  for (int mt = 0; mt < 8; ++mt) {
#pragma unroll
    for (int r = 0; r < 4; ++r) {
      float v = sacc[mt][r] * 0.125f + bias[mt][r];  // scale = H^-0.5 ; pad bias
      sacc[mt][r] = v;
      m = fmaxf(m, v);
    }
  }
  m = fmaxf(m, __shfl_xor(m, 16));
  m = fmaxf(m, __shfl_xor(m, 32));
  float sum = 0.0f;
#pragma unroll
  for (int mt = 0; mt < 8; ++mt) {
#pragma unroll
    for (int r = 0; r < 4; ++r) {
      const int s = mt * 16 + g4 * 4 + r;
      float p = __expf(sacc[mt][r] - m);
      p = (s <= tq) ? p : 0.0f;               // causal, multiplicative
      sacc[mt][r] = p;
      sum += p;
    }
  }
  sum += __shfl_xor(sum, 16);
  sum += __shfl_xor(sum, 32);
  const float inv = 1.0f / sum;  // >0: col 0 always valid & causal-visible

  // P bounce through wave-private LDS (X0/X1 dead after B5).
  // Lane holds P[t=16w+l15][s=mt*16+g4*4+0..3] -> P row = l15,
  // chunk c = mt*2+(g4>>1) (^l15 swizzle), 8B half = g4&1.
  // No barrier: slice is wave-private on both sides (R1/R13-proven).
  uint8_t* const Pr = (l15 < 8) ? (X0 + w * 2048 + l15 * 256)
                                : (X1 + w * 2048 + (l15 - 8) * 256);
#pragma unroll
  for (int mt = 0; mt < 8; ++mt) {
    u32x2 d = { cvt2(sacc[mt][0], sacc[mt][1]), cvt2(sacc[mt][2], sacc[mt][3]) };
    const int c = mt * 2 + (g4 >> 1);
    *(u32x2*)(Pr + (((c ^ l15)) << 4) + ((g4 & 1) << 3)) = d;
  }

  // OUT^T = V^T @ P^T : A = V^T from Vb rows, B = P rows (lane row = l15)
  f32x4 oacc[4];
#pragma unroll
  for (int vt = 0; vt < 4; ++vt) oacc[vt] = {0, 0, 0, 0};
  __builtin_amdgcn_s_setprio(1);
#pragma unroll
  for (int ks = 0; ks < 4; ++ks) {
    u32x4 pb = *(const u32x4*)(Pr + ((((ks * 4 + g4) ^ l15)) << 4));
#pragma unroll
    for (int vt = 0; vt < 4; ++vt) {
      const int vrow = vt * 16 + l15;
      u32x4 vf = *(const u32x4*)(Vb + (vrow << 8) + ((((ks * 4 + g4) ^ (vrow & 7))) << 4));
      oacc[vt] = mfma16(vf, pb, oacc[vt]);
    }
  }
  __builtin_amdgcn_s_setprio(0);

  // epilogue: out[t][h], t = 16w + l15, h = vt*16 + g4*4 + r ; fold 1/sum
  float* const ob = out + (size_t)b * 8192 + (size_t)tq * 64;
#pragma unroll
  for (int vt = 0; vt < 4; ++vt) {
    f32x4 o = { oacc[vt][0] * inv, oacc[vt][1] * inv,
                oacc[vt][2] * inv, oacc[vt][3] * inv };
    *(f32x4*)(ob + vt * 16 + g4 * 4) = o;
  }
}

extern "C" void kernel_launch(void* const* d_in, const int* in_sizes, int n_in,
                              void* d_out, int out_size, void* d_ws, size_t ws_size,
                              hipStream_t stream) {
  const float* src = (const float*)d_in[0];
  const float* tgt = (const float*)d_in[1];
  const void*  msk = d_in[2];
  const float* Wq  = (const float*)d_in[3];
  const float* Wk  = (const float*)d_in[4];
  const float* Wv  = (const float*)d_in[5];
  uint32_t* ws = (uint32_t*)d_ws;  // 48KB W frags + mask-dtype flag
  float* out = (float*)d_out;
  const int B = in_sizes[0] / (128 * 128);

  hipLaunchKernelGGL(prep_w, dim3(49), dim3(64), 0, stream, Wq, Wk, Wv, msk, ws);
  hipLaunchKernelGGL(attn_fused, dim3(B), dim3(512), 0, stream,
                     src, tgt, msk, ws, out);
}

// Round 15
// 154.445 us; speedup vs baseline: 1.0437x; 1.0437x over previous
//
#include <hip/hip_runtime.h>
#include <stdint.h>

// Fused attention head: out = softmax(mask((Tgt@Wq)(Src@Wk)^T * H^-0.5)) @ (Src@Wv)
// B=4096, T=128, C=128, H=64. One block/batch, 512 threads (8 waves).
// R15: TWO barriers total. Full-src staged in one 32KB buffer (Qb deleted ->
// same 64.5KB LDS as R13); Q projected from global-loaded registers with
// R10-proven shuffle redistribution; 17 loads/thread in flight at head.
// Tail = R13 verbatim (QK, softmax, P bounce into dead EMB, PV).

typedef uint32_t u32x2 __attribute__((ext_vector_type(2)));
typedef uint32_t u32x4 __attribute__((ext_vector_type(4)));
typedef float    f32x4 __attribute__((ext_vector_type(4)));
typedef __bf16   bf16x8 __attribute__((ext_vector_type(8)));

static __device__ __forceinline__ uint32_t pack2(float a, float b) {  // RNE (prep kernel)
  uint32_t ua = __builtin_bit_cast(uint32_t, a);
  uint32_t ub = __builtin_bit_cast(uint32_t, b);
  ua += 0x7FFFu + ((ua >> 16) & 1u);
  ub += 0x7FFFu + ((ub >> 16) & 1u);
  return (ua >> 16) | (ub & 0xFFFF0000u);
}
// compiler-generated f32->bf16 RNE pair (HW-proven R9-R14)
static __device__ __forceinline__ uint32_t cvt2(float a, float b) {
  uint16_t lo = __builtin_bit_cast(uint16_t, (__bf16)a);
  uint16_t hi = __builtin_bit_cast(uint16_t, (__bf16)b);
  return (uint32_t)lo | ((uint32_t)hi << 16);
}
static __device__ __forceinline__ f32x4 mfma16(u32x4 a, u32x4 b, f32x4 c) {
  return __builtin_amdgcn_mfma_f32_16x16x32_bf16(
      __builtin_bit_cast(bf16x8, a), __builtin_bit_cast(bf16x8, b), c, 0, 0, 0);
}

// ---- prep: pack Wq/Wk/Wv into MFMA frag layout in ws; detect mask dtype ----
// frag f=(m*4+ct)*4+ks, lane l: 8 bf16 of W[c][h], h=ct*16+(l&15), c=ks*32+(l>>4)*8+0..7.
// Serves BOTH as B-frag of W (V proj) and A-frag of W^T (K/Q proj).
__global__ void prep_w(const float* __restrict__ Wq, const float* __restrict__ Wk,
                       const float* __restrict__ Wv, const void* __restrict__ mask,
                       uint32_t* __restrict__ ws) {
  const int blk = blockIdx.x;
  const int l = threadIdx.x;  // 0..63
  if (blk < 48) {
    const int m  = blk >> 4;
    const int ct = (blk >> 2) & 3;
    const int ks = blk & 3;
    const float* W = (m == 0) ? Wq : ((m == 1) ? Wk : Wv);
    const int h  = ct * 16 + (l & 15);
    const int c0 = ks * 32 + (l >> 4) * 8;
    u32x4 v;
#pragma unroll
    for (int p = 0; p < 4; ++p)
      v[p] = pack2(W[(c0 + 2 * p) * 64 + h], W[(c0 + 2 * p + 1) * 64 + h]);
    ((u32x4*)ws)[blk * 64 + l] = v;
  } else {
    // mask dtype detect: 0=int32(0/1), 1=bytes, 2=float
    const uint32_t* mw = (const uint32_t*)mask;
    int fl = 0;
    for (int i = l * 16; i < l * 16 + 16; ++i) {
      uint32_t x = mw[i];
      if (x == 0x3F800000u) fl = 2;
      else if (x > 1u && fl != 2) fl = 1;
    }
#pragma unroll
    for (int off = 32; off > 0; off >>= 1) {
      int o = __shfl_down(fl, off);
      fl = (o > fl) ? o : fl;
    }
    if (l == 0) ws[12288] = (uint32_t)fl;
  }
}

// LDS (64.5 KB -> 2 blocks/CU):
//  EMB [128][128] bf16 swz (32K)  FULL src staging; tail: wave-private P (4KB/wave)
//  Kb  [128][64]  bf16 swz (16K)  K^T[s][h]
//  Vb  [64][128]  bf16 swz (16K)  V^T[h][s]
//  BIAS[128] f32
// Swizzle: 16B chunk c of row r stored at chunk (c ^ (r&7)); P uses (c ^ (t&15)).
__global__ __launch_bounds__(512, 2) void attn_fused(
    const float* __restrict__ src, const float* __restrict__ tgt,
    const void* __restrict__ mask, const uint32_t* __restrict__ ws,
    float* __restrict__ out) {
  __shared__ __align__(16) uint8_t lds[66048];
  uint8_t* const EMB = lds;
  uint8_t* const Kb  = lds + 32768;
  uint8_t* const Vb  = lds + 49152;
  float*  const BIAS = (float*)(lds + 65536);

  const int b   = blockIdx.x;
  const int tid = (int)threadIdx.x;
  const int l   = tid & 63;
  const int w   = tid >> 6;      // wave 0..7
  const int l15 = l & 15;
  const int g4  = l >> 4;        // 0..3
  const int ct  = w & 3;         // this wave's h-tile for K/V projections
  const int sg  = (w >> 2) * 2;  // first local s-tile (0 or 2) within each half
  const int tq  = 16 * w + l15;  // this lane's output row t

  const u32x4* wsv = (const u32x4*)ws;
  const int mflag = (int)ws[12288];
  const float* const srcb = src + (size_t)b * 16384;
  const float* const tgtb = tgt + (size_t)b * 16384;

  // ---- HEAD: issue all global loads at once (17 per thread in flight) ----
  f32x4 qv[8];   // Q rows: tgt[tq][ks*32 + g4*8 + 0..7]
  {
    const float* pq = tgtb + tq * 128 + g4 * 8;
#pragma unroll
    for (int ks = 0; ks < 4; ++ks) {
      qv[2 * ks]     = *(const f32x4*)(pq + ks * 32);
      qv[2 * ks + 1] = *(const f32x4*)(pq + ks * 32 + 4);
    }
  }
  f32x4 pf[8];   // full src: 128B/thread
#pragma unroll
  for (int p = 0; p < 8; ++p)
    pf[p] = *(const f32x4*)(srcb + tid * 4 + p * 2048);
  float biasv = 0.0f;
  if (tid < 128) {
    bool valid;
    if (mflag == 1)      valid = ((const uint8_t*)mask)[b * 128 + tid] != 0;
    else if (mflag == 0) valid = ((const int*)mask)[b * 128 + tid] != 0;
    else                 valid = ((const float*)mask)[b * 128 + tid] != 0.0f;
    biasv = valid ? 0.0f : -1e30f;
  }

  // ---- stage full src -> EMB (swz), write bias ----
#pragma unroll
  for (int p = 0; p < 8; ++p) {
    const int c   = tid + p * 512;
    const int row = c >> 5;     // 0..127
    const int cc  = c & 31;     // f32x4 chunk within row
    u32x2 d = { cvt2(pf[p][0], pf[p][1]), cvt2(pf[p][2], pf[p][3]) };
    *(u32x2*)(EMB + (row << 8) + ((((cc >> 1) ^ (row & 7))) << 4) + ((cc & 1) << 3)) = d;
  }
  if (tid < 128) BIAS[tid] = biasv;
  __syncthreads();                 // B1: EMB(full)/BIAS ready

  // ---- projKV over full EMB: wave = h-tile ct, s-tiles {half*64 + (sg+i)*16} ----
  u32x4 wk[4], wv[4];
#pragma unroll
  for (int ks = 0; ks < 4; ++ks) {
    wk[ks] = wsv[((4 + ct) * 4 + ks) * 64 + l];   // A-frag of Wk^T
    wv[ks] = wsv[((8 + ct) * 4 + ks) * 64 + l];   // B-frag of Wv
  }
#pragma unroll
  for (int half = 0; half < 2; ++half) {
#pragma unroll
    for (int i = 0; i < 2; ++i) {
      const int s16 = half * 64 + (sg + i) * 16;   // s-tile base
      const int row = s16 + l15;                   // EMB row = s
      f32x4 cK = {0, 0, 0, 0}, cV = {0, 0, 0, 0};
#pragma unroll
      for (int ks = 0; ks < 4; ++ks) {
        u32x4 e = *(const u32x4*)(EMB + (row << 8) + ((((ks * 4 + g4) ^ (row & 7))) << 4));
        cK = mfma16(wk[ks], e, cK);   // C[h][s]
        cV = mfma16(e, wv[ks], cV);   // C[s][h]
      }
      const int s  = row;                              // K^T: n=s per-lane col
      const int h0 = ct * 16 + g4 * 4;                 //      m=h rows (packed)
      u32x2 dk = { cvt2(cK[0], cK[1]), cvt2(cK[2], cK[3]) };
      *(u32x2*)(Kb + (s << 7) + ((((h0 >> 3) ^ (s & 7))) << 4) + ((h0 & 7) << 1)) = dk;
      const int s0 = s16 + g4 * 4;                     // V: m=s rows (packed)
      const int h  = ct * 16 + l15;                    //    n=h per-lane col
      u32x2 dv = { cvt2(cV[0], cV[1]), cvt2(cV[2], cV[3]) };
      *(u32x2*)(Vb + (h << 8) + ((((s0 >> 3) ^ (h & 7))) << 4) + ((s0 & 7) << 1)) = dv;
    }
  }

  // ---- projQ from qv regs (R10-proven): all 64 h for own t-tile ----
  // qp[ctq*2+p] = bf16x2 of Q^T[h = ctq*16 + g4*4 + 2p + {0,1}][t]
  uint32_t qp[8];
  {
    f32x4 c0 = {0,0,0,0}, c1 = {0,0,0,0}, c2 = {0,0,0,0}, c3 = {0,0,0,0};
#pragma unroll
    for (int ks = 0; ks < 4; ++ks) {
      u32x4 e = { cvt2(qv[2*ks][0], qv[2*ks][1]), cvt2(qv[2*ks][2], qv[2*ks][3]),
                  cvt2(qv[2*ks+1][0], qv[2*ks+1][1]), cvt2(qv[2*ks+1][2], qv[2*ks+1][3]) };
      c0 = mfma16(wsv[(0  + ks) * 64 + l], e, c0);
      c1 = mfma16(wsv[(4  + ks) * 64 + l], e, c1);
      c2 = mfma16(wsv[(8  + ks) * 64 + l], e, c2);
      c3 = mfma16(wsv[(12 + ks) * 64 + l], e, c3);
    }
    qp[0] = cvt2(c0[0], c0[1]); qp[1] = cvt2(c0[2], c0[3]);
    qp[2] = cvt2(c1[0], c1[1]); qp[3] = cvt2(c1[2], c1[3]);
    qp[4] = cvt2(c2[0], c2[1]); qp[5] = cvt2(c2[2], c2[3]);
    qp[6] = cvt2(c3[0], c3[1]); qp[7] = cvt2(c3[2], c3[3]);
  }

  // ---- Q C-frag -> B-frag via double-pull shuffles (R10-proven) ----
  const int hi2 = g4 >> 1;
  const int sA  = ((g4 & 1) * 2) * 16 + l15;  // src lane for words m=0,1
  const int sB  = sA + 16;                    // src lane for words m=2,3
  u32x4 qB[2];
#pragma unroll
  for (int ks = 0; ks < 2; ++ks) {
    uint32_t a0 = (uint32_t)__shfl((int)qp[4 * ks + 0], sA);
    uint32_t a1 = (uint32_t)__shfl((int)qp[4 * ks + 1], sA);
    uint32_t a2 = (uint32_t)__shfl((int)qp[4 * ks + 2], sA);
    uint32_t a3 = (uint32_t)__shfl((int)qp[4 * ks + 3], sA);
    uint32_t b0 = (uint32_t)__shfl((int)qp[4 * ks + 0], sB);
    uint32_t b1 = (uint32_t)__shfl((int)qp[4 * ks + 1], sB);
    uint32_t b2 = (uint32_t)__shfl((int)qp[4 * ks + 2], sB);
    uint32_t b3 = (uint32_t)__shfl((int)qp[4 * ks + 3], sB);
    qB[ks][0] = hi2 ? a2 : a0;
    qB[ks][1] = hi2 ? a3 : a1;
    qB[ks][2] = hi2 ? b2 : b0;
    qB[ks][3] = hi2 ? b3 : b1;
  }

  __syncthreads();                 // B2: Kb/Vb complete; EMB dead
  // ---- free-run tail (R13 verbatim): no more barriers ----

  f32x4 sacc[8];
#pragma unroll
  for (int mt = 0; mt < 8; ++mt) sacc[mt] = {0, 0, 0, 0};
  __builtin_amdgcn_s_setprio(1);
#pragma unroll
  for (int mt = 0; mt < 8; ++mt) {
    const int srow = mt * 16 + l15;
    u32x4 k0 = *(const u32x4*)(Kb + (srow << 7) + (((g4 ^ (srow & 7))) << 4));
    u32x4 k1 = *(const u32x4*)(Kb + (srow << 7) + ((((4 + g4) ^ (srow & 7))) << 4));
    sacc[mt] = mfma16(k0, qB[0], sacc[mt]);
    sacc[mt] = mfma16(k1, qB[1], sacc[mt]);
  }
  __builtin_amdgcn_s_setprio(0);

  // softmax over s (per lane: 32 s-values of row t; reduce across 4-lane group)
  float m = -3.0e38f;
#pragma unroll
  for (int mt = 0; mt < 8; ++mt) {
    f32x4 b4 = *(const f32x4*)(BIAS + mt * 16 + g4 * 4);
#pragma unroll
    for (int r = 0; r < 4; ++r) {
      float v = sacc[mt][r] * 0.125f + b4[r];  // scale = H^-0.5 ; pad bias -1e30
      sacc[mt][r] = v;
      m = fmaxf(m, v);
    }
  }
  m = fmaxf(m, __shfl_xor(m, 16));
  m = fmaxf(m, __shfl_xor(m, 32));
  float sum = 0.0f;
#pragma unroll
  for (int mt = 0; mt < 8; ++mt) {
#pragma unroll
    for (int r = 0; r < 4; ++r) {
      const int s = mt * 16 + g4 * 4 + r;
      float p = __expf(sacc[mt][r] - m);
      p = (s <= tq) ? p : 0.0f;               // causal, multiplicative
      sacc[mt][r] = p;
      sum += p;
    }
  }
  sum += __shfl_xor(sum, 16);
  sum += __shfl_xor(sum, 32);
  const float inv = 1.0f / sum;  // >0: col 0 always valid & causal-visible

  // P bounce through wave-private LDS slice of dead EMB (4KB/wave, rows = l15).
  // Lane holds P[t=16w+l15][s=mt*16+g4*4+0..3] -> chunk c = mt*2+(g4>>1),
  // byte = ((c ^ l15) << 4) + ((g4&1)<<3). No barrier (R1/R13-proven).
  uint8_t* const Pr = EMB + (w << 12) + (l15 << 8);
#pragma unroll
  for (int mt = 0; mt < 8; ++mt) {
    u32x2 d = { cvt2(sacc[mt][0], sacc[mt][1]), cvt2(sacc[mt][2], sacc[mt][3]) };
    const int c = mt * 2 + (g4 >> 1);
    *(u32x2*)(Pr + (((c ^ l15)) << 4) + ((g4 & 1) << 3)) = d;
  }

  // OUT^T = V^T @ P^T : A = V^T from Vb rows, B = P rows (lane row = l15)
  f32x4 oacc[4];
#pragma unroll
  for (int vt = 0; vt < 4; ++vt) oacc[vt] = {0, 0, 0, 0};
  __builtin_amdgcn_s_setprio(1);
#pragma unroll
  for (int ks = 0; ks < 4; ++ks) {
    u32x4 pb = *(const u32x4*)(Pr + ((((ks * 4 + g4) ^ l15)) << 4));
#pragma unroll
    for (int vt = 0; vt < 4; ++vt) {
      const int vrow = vt * 16 + l15;
      u32x4 vf = *(const u32x4*)(Vb + (vrow << 8) + ((((ks * 4 + g4) ^ (vrow & 7))) << 4));
      oacc[vt] = mfma16(vf, pb, oacc[vt]);
    }
  }
  __builtin_amdgcn_s_setprio(0);

  // epilogue: out[t][h], t = 16w + l15, h = vt*16 + g4*4 + r ; fold 1/sum
  float* const ob = out + (size_t)b * 8192 + (size_t)tq * 64;
#pragma unroll
  for (int vt = 0; vt < 4; ++vt) {
    f32x4 o = { oacc[vt][0] * inv, oacc[vt][1] * inv,
                oacc[vt][2] * inv, oacc[vt][3] * inv };
    *(f32x4*)(ob + vt * 16 + g4 * 4) = o;
  }
}

extern "C" void kernel_launch(void* const* d_in, const int* in_sizes, int n_in,
                              void* d_out, int out_size, void* d_ws, size_t ws_size,
                              hipStream_t stream) {
  const float* src = (const float*)d_in[0];
  const float* tgt = (const float*)d_in[1];
  const void*  msk = d_in[2];
  const float* Wq  = (const float*)d_in[3];
  const float* Wk  = (const float*)d_in[4];
  const float* Wv  = (const float*)d_in[5];
  uint32_t* ws = (uint32_t*)d_ws;  // 48KB W frags + mask-dtype flag
  float* out = (float*)d_out;
  const int B = in_sizes[0] / (128 * 128);

  hipLaunchKernelGGL(prep_w, dim3(49), dim3(64), 0, stream, Wq, Wk, Wv, msk, ws);
  hipLaunchKernelGGL(attn_fused, dim3(B), dim3(512), 0, stream,
                     src, tgt, msk, ws, out);
}

// Round 16
// 142.324 us; speedup vs baseline: 1.1325x; 1.0852x over previous
//
#include <hip/hip_runtime.h>
#include <stdint.h>

// Fused attention head: out = softmax(mask((Tgt@Wq)(Src@Wk)^T * H^-0.5)) @ (Src@Wv)
// B=4096, T=128, C=128, H=64. One block/batch, 512 threads (8 waves).
// R16 = R13 (champion, 140.9us) with ONE change: all 8 __syncthreads replaced
// by fused asm "s_waitcnt lgkmcnt(0); s_barrier" — vmcnt NOT drained, so the
// one-phase-early global prefetch stays in flight across barriers (T4).
// R3 tested this construct but NaN'd from the (now-removed) v_cvt_pk asm;
// the R4/R5 bisect exonerated the barrier — this is its clean retest.

typedef uint32_t u32x2 __attribute__((ext_vector_type(2)));
typedef uint32_t u32x4 __attribute__((ext_vector_type(4)));
typedef float    f32x4 __attribute__((ext_vector_type(4)));
typedef __bf16   bf16x8 __attribute__((ext_vector_type(8)));

static __device__ __forceinline__ uint32_t pack2(float a, float b) {  // RNE (prep kernel)
  uint32_t ua = __builtin_bit_cast(uint32_t, a);
  uint32_t ub = __builtin_bit_cast(uint32_t, b);
  ua += 0x7FFFu + ((ua >> 16) & 1u);
  ub += 0x7FFFu + ((ub >> 16) & 1u);
  return (ua >> 16) | (ub & 0xFFFF0000u);
}
// compiler-generated f32->bf16 RNE pair (HW-proven R9-R15)
static __device__ __forceinline__ uint32_t cvt2(float a, float b) {
  uint16_t lo = __builtin_bit_cast(uint16_t, (__bf16)a);
  uint16_t hi = __builtin_bit_cast(uint16_t, (__bf16)b);
  return (uint32_t)lo | ((uint32_t)hi << 16);
}
static __device__ __forceinline__ f32x4 mfma16(u32x4 a, u32x4 b, f32x4 c) {
  return __builtin_amdgcn_mfma_f32_16x16x32_bf16(
      __builtin_bit_cast(bf16x8, a), __builtin_bit_cast(bf16x8, b), c, 0, 0, 0);
}
// Barrier that orders LDS only: lgkmcnt(0) + s_barrier in ONE asm (no gap for
// IR-level LDS-load hoisting), memory clobber blocks compiler reordering,
// sched_barrier fences the scheduler. vmcnt deliberately NOT drained: in-flight
// global loads feed only private registers; compiler waits at first use.
static __device__ __forceinline__ void barrier_lgkm() {
  __builtin_amdgcn_sched_barrier(0);
  asm volatile("s_waitcnt lgkmcnt(0)\n\ts_barrier" ::: "memory");
  __builtin_amdgcn_sched_barrier(0);
}

// ---- prep: pack Wq/Wk/Wv into MFMA frag layout in ws; detect mask dtype ----
// frag f=(m*4+ct)*4+ks, lane l: 8 bf16 of W[c][h], h=ct*16+(l&15), c=ks*32+(l>>4)*8+0..7.
// Serves BOTH as B-frag of W (V proj) and A-frag of W^T (K/Q proj).
__global__ void prep_w(const float* __restrict__ Wq, const float* __restrict__ Wk,
                       const float* __restrict__ Wv, const void* __restrict__ mask,
                       uint32_t* __restrict__ ws) {
  const int blk = blockIdx.x;
  const int l = threadIdx.x;  // 0..63
  if (blk < 48) {
    const int m  = blk >> 4;
    const int ct = (blk >> 2) & 3;
    const int ks = blk & 3;
    const float* W = (m == 0) ? Wq : ((m == 1) ? Wk : Wv);
    const int h  = ct * 16 + (l & 15);
    const int c0 = ks * 32 + (l >> 4) * 8;
    u32x4 v;
#pragma unroll
    for (int p = 0; p < 4; ++p)
      v[p] = pack2(W[(c0 + 2 * p) * 64 + h], W[(c0 + 2 * p + 1) * 64 + h]);
    ((u32x4*)ws)[blk * 64 + l] = v;
  } else {
    // mask dtype detect: 0=int32(0/1), 1=bytes, 2=float
    const uint32_t* mw = (const uint32_t*)mask;
    int fl = 0;
    for (int i = l * 16; i < l * 16 + 16; ++i) {
      uint32_t x = mw[i];
      if (x == 0x3F800000u) fl = 2;
      else if (x > 1u && fl != 2) fl = 1;
    }
#pragma unroll
    for (int off = 32; off > 0; off >>= 1) {
      int o = __shfl_down(fl, off);
      fl = (o > fl) ? o : fl;
    }
    if (l == 0) ws[12288] = (uint32_t)fl;
  }
}

// LDS (64.5 KB -> 2 blocks/CU):
//  EMB [64][128] bf16 swz (16K)  staging; later: wave-private P rows t%16 = 0..7
//  Qb  [128][64] bf16 swz (16K)  Q^T store; later: wave-private P rows 8..15
//  Kb  [128][64] bf16 swz (16K)
//  Vb  [64][128] bf16 swz (16K)  (v^T: row=h, col=s)
//  BIAS[128] f32
// Swizzle: 16B chunk c of row r stored at chunk (c ^ (r&7)); P uses (c ^ (t&15)).
__global__ __launch_bounds__(512, 4) void attn_fused(
    const float* __restrict__ src, const float* __restrict__ tgt,
    const void* __restrict__ mask, const uint32_t* __restrict__ ws,
    float* __restrict__ out) {
  __shared__ __align__(16) uint8_t lds[66048];
  uint8_t* const EMB = lds;
  uint8_t* const Qb  = lds + 16384;
  uint8_t* const Kb  = lds + 32768;
  uint8_t* const Vb  = lds + 49152;
  float*  const BIAS = (float*)(lds + 65536);

  const int b   = blockIdx.x;
  const int tid = (int)threadIdx.x;
  const int l   = tid & 63;
  const int w   = tid >> 6;      // wave 0..7
  const int l15 = l & 15;
  const int g4  = l >> 4;        // 0..3
  const int ct  = w & 3;         // this wave's h-tile for projections
  const int sg  = (w >> 2) * 2;  // first local s/t-tile (0 or 2)

  const u32x4* wsv = (const u32x4*)ws;
  const int mflag = (int)ws[12288];
  const float* const srcb = src + (size_t)b * 16384;
  const float* const tgtb = tgt + (size_t)b * 16384;

  u32x4 wk[4], wv[4], wq[4];
#pragma unroll
  for (int ks = 0; ks < 4; ++ks) {
    wk[ks] = wsv[((4 + ct) * 4 + ks) * 64 + l];   // A-frag of Wk^T
    wv[ks] = wsv[((8 + ct) * 4 + ks) * 64 + l];   // B-frag of Wv
  }

  // staging: thread covers 4 fully-coalesced f32x4 chunks (tid + p*512)
  f32x4 pf[4];
  auto stage_load = [&](const float* gbase) {
#pragma unroll
    for (int p = 0; p < 4; ++p)
      pf[p] = *(const f32x4*)(gbase + tid * 4 + p * 2048);
  };
  auto stage_write = [&]() {
#pragma unroll
    for (int p = 0; p < 4; ++p) {
      const int c   = tid + p * 512;
      const int row = c >> 5;     // 0..63
      const int cc  = c & 31;     // f32x4 chunk within row
      u32x2 d = { cvt2(pf[p][0], pf[p][1]), cvt2(pf[p][2], pf[p][3]) };
      *(u32x2*)(EMB + (row << 8) + ((((cc >> 1) ^ (row & 7))) << 4) + ((cc & 1) << 3)) = d;
    }
  };

  // K^T = Wk^T @ Src^T and V = Src @ Wv over one staged 64-row half.
  auto projKV = [&](int half) {
#pragma unroll
    for (int i = 0; i < 2; ++i) {
      const int st  = sg + i;            // local 16-row tile 0..3
      const int row = st * 16 + l15;     // EMB row
      f32x4 cK = {0, 0, 0, 0}, cV = {0, 0, 0, 0};
#pragma unroll
      for (int ks = 0; ks < 4; ++ks) {
        u32x4 e = *(const u32x4*)(EMB + (row << 8) + ((((ks * 4 + g4) ^ (row & 7))) << 4));
        cK = mfma16(wk[ks], e, cK);   // C[h][s]
        cV = mfma16(e, wv[ks], cV);   // C[s][h]
      }
      const int s  = half * 64 + st * 16 + l15;       // K^T: n=s per-lane col
      const int h0 = ct * 16 + g4 * 4;                //      m=h rows (packed)
      u32x2 dk = { cvt2(cK[0], cK[1]), cvt2(cK[2], cK[3]) };
      *(u32x2*)(Kb + (s << 7) + ((((h0 >> 3) ^ (s & 7))) << 4) + ((h0 & 7) << 1)) = dk;
      const int s0 = half * 64 + st * 16 + g4 * 4;    // V: m=s rows (packed)
      const int h  = ct * 16 + l15;                   //    n=h per-lane col
      u32x2 dv = { cvt2(cV[0], cV[1]), cvt2(cV[2], cV[3]) };
      *(u32x2*)(Vb + (h << 8) + ((((s0 >> 3) ^ (h & 7))) << 4) + ((s0 & 7) << 1)) = dv;
    }
  };
  auto projQ = [&](int half) {
#pragma unroll
    for (int i = 0; i < 2; ++i) {
      const int st  = sg + i;
      const int row = st * 16 + l15;
      f32x4 cQ = {0, 0, 0, 0};
#pragma unroll
      for (int ks = 0; ks < 4; ++ks) {
        u32x4 e = *(const u32x4*)(EMB + (row << 8) + ((((ks * 4 + g4) ^ (row & 7))) << 4));
        cQ = mfma16(wq[ks], e, cQ);
      }
      const int t  = half * 64 + st * 16 + l15;
      const int h0 = ct * 16 + g4 * 4;
      u32x2 dq = { cvt2(cQ[0], cQ[1]), cvt2(cQ[2], cQ[3]) };
      *(u32x2*)(Qb + (t << 7) + ((((h0 >> 3) ^ (t & 7))) << 4) + ((h0 & 7) << 1)) = dq;
    }
  };

  // ---- pipeline: loads issued one phase early; lgkm-only barriers keep the
  //      prefetch in flight (vmcnt waits land at first register use) ----
  stage_load(srcb);
  float biasv = 0.0f;
  if (tid < 128) {
    bool valid;
    if (mflag == 1)      valid = ((const uint8_t*)mask)[b * 128 + tid] != 0;
    else if (mflag == 0) valid = ((const int*)mask)[b * 128 + tid] != 0;
    else                 valid = ((const float*)mask)[b * 128 + tid] != 0.0f;
    biasv = valid ? 0.0f : -1e30f;
  }
  stage_write();
  if (tid < 128) BIAS[tid] = biasv;
  barrier_lgkm();
  stage_load(srcb + 8192);
  projKV(0);
  barrier_lgkm();
  stage_write();
  barrier_lgkm();
  stage_load(tgtb);
  projKV(1);
#pragma unroll
  for (int ks = 0; ks < 4; ++ks)
    wq[ks] = wsv[(ct * 4 + ks) * 64 + l];  // A-frag of Wq^T
  barrier_lgkm();
  stage_write();
  barrier_lgkm();
  stage_load(tgtb + 8192);
  projQ(0);
  barrier_lgkm();
  stage_write();
  barrier_lgkm();
  projQ(1);
  barrier_lgkm();
  // ------------- no more barriers: waves free-run through QK/softmax/PV -------------

  // S^T = K @ Q^T : wave w owns t-tile w. Per lane: col t = 16w + l15,
  // rows s = mt*16 + g4*4 + r  (C layout: col = lane&15, row = (lane>>4)*4 + reg).
  const int tq = 16 * w + l15;
  u32x4 qf0 = *(const u32x4*)(Qb + (tq << 7) + (((g4 ^ (tq & 7))) << 4));
  u32x4 qf1 = *(const u32x4*)(Qb + (tq << 7) + ((((4 + g4) ^ (tq & 7))) << 4));

  f32x4 sacc[8];
#pragma unroll
  for (int mt = 0; mt < 8; ++mt) sacc[mt] = {0, 0, 0, 0};
  __builtin_amdgcn_s_setprio(1);
#pragma unroll
  for (int mt = 0; mt < 8; ++mt) {
    const int srow = mt * 16 + l15;
    u32x4 k0 = *(const u32x4*)(Kb + (srow << 7) + (((g4 ^ (srow & 7))) << 4));
    u32x4 k1 = *(const u32x4*)(Kb + (srow << 7) + ((((4 + g4) ^ (srow & 7))) << 4));
    sacc[mt] = mfma16(k0, qf0, sacc[mt]);
    sacc[mt] = mfma16(k1, qf1, sacc[mt]);
  }
  __builtin_amdgcn_s_setprio(0);

  // softmax over s (per lane: 32 s-values of row t; reduce across 4-lane group)
  float m = -3.0e38f;
#pragma unroll
  for (int mt = 0; mt < 8; ++mt) {
    f32x4 b4 = *(const f32x4*)(BIAS + mt * 16 + g4 * 4);
#pragma unroll
    for (int r = 0; r < 4; ++r) {
      float v = sacc[mt][r] * 0.125f + b4[r];  // scale = H^-0.5 ; pad bias -1e30
      sacc[mt][r] = v;
      m = fmaxf(m, v);
    }
  }
  m = fmaxf(m, __shfl_xor(m, 16));
  m = fmaxf(m, __shfl_xor(m, 32));
  float sum = 0.0f;
#pragma unroll
  for (int mt = 0; mt < 8; ++mt) {
#pragma unroll
    for (int r = 0; r < 4; ++r) {
      const int s = mt * 16 + g4 * 4 + r;
      float p = __expf(sacc[mt][r] - m);
      p = (s <= tq) ? p : 0.0f;               // causal, multiplicative
      sacc[mt][r] = p;
      sum += p;
    }
  }
  sum += __shfl_xor(sum, 16);
  sum += __shfl_xor(sum, 32);
  const float inv = 1.0f / sum;  // >0: col 0 always valid & causal-visible

  // P bounce through wave-private LDS (EMB rows 8w..8w+7 and own Qb rows dead).
  // Lane holds P[t=16w+l15][s=mt*16+g4*4+0..3] -> P row = l15,
  // chunk c = mt*2+(g4>>1) (^l15 swizzle), 8B half = g4&1.
  // No barrier: slice is wave-private on both sides (R1/R13-proven).
  uint8_t* const Pr = (l15 < 8) ? (EMB + w * 2048 + l15 * 256)
                                : (Qb + w * 2048 + (l15 - 8) * 256);
#pragma unroll
  for (int mt = 0; mt < 8; ++mt) {
    u32x2 d = { cvt2(sacc[mt][0], sacc[mt][1]), cvt2(sacc[mt][2], sacc[mt][3]) };
    const int c = mt * 2 + (g4 >> 1);
    *(u32x2*)(Pr + (((c ^ l15)) << 4) + ((g4 & 1) << 3)) = d;
  }

  // OUT^T = V^T @ P^T : A = V^T from Vb rows, B = P rows (lane row = l15)
  f32x4 oacc[4];
#pragma unroll
  for (int vt = 0; vt < 4; ++vt) oacc[vt] = {0, 0, 0, 0};
  __builtin_amdgcn_s_setprio(1);
#pragma unroll
  for (int ks = 0; ks < 4; ++ks) {
    u32x4 pb = *(const u32x4*)(Pr + ((((ks * 4 + g4) ^ l15)) << 4));
#pragma unroll
    for (int vt = 0; vt < 4; ++vt) {
      const int vrow = vt * 16 + l15;
      u32x4 vf = *(const u32x4*)(Vb + (vrow << 8) + ((((ks * 4 + g4) ^ (vrow & 7))) << 4));
      oacc[vt] = mfma16(vf, pb, oacc[vt]);
    }
  }
  __builtin_amdgcn_s_setprio(0);

  // epilogue: out[t][h], t = 16w + l15, h = vt*16 + g4*4 + r ; fold 1/sum
  float* const ob = out + (size_t)b * 8192 + (size_t)tq * 64;
#pragma unroll
  for (int vt = 0; vt < 4; ++vt) {
    f32x4 o = { oacc[vt][0] * inv, oacc[vt][1] * inv,
                oacc[vt][2] * inv, oacc[vt][3] * inv };
    *(f32x4*)(ob + vt * 16 + g4 * 4) = o;
  }
}

extern "C" void kernel_launch(void* const* d_in, const int* in_sizes, int n_in,
                              void* d_out, int out_size, void* d_ws, size_t ws_size,
                              hipStream_t stream) {
  const float* src = (const float*)d_in[0];
  const float* tgt = (const float*)d_in[1];
  const void*  msk = d_in[2];
  const float* Wq  = (const float*)d_in[3];
  const float* Wk  = (const float*)d_in[4];
  const float* Wv  = (const float*)d_in[5];
  uint32_t* ws = (uint32_t*)d_ws;  // 48KB W frags + mask-dtype flag
  float* out = (float*)d_out;
  const int B = in_sizes[0] / (128 * 128);

  hipLaunchKernelGGL(prep_w, dim3(49), dim3(64), 0, stream, Wq, Wk, Wv, msk, ws);
  hipLaunchKernelGGL(attn_fused, dim3(B), dim3(512), 0, stream,
                     src, tgt, msk, ws, out);
}